// Round 1
// baseline (3552.241 us; speedup 1.0000x reference)
//
#include <hip/hip_runtime.h>
#include <math.h>

// Problem: 2-layer GCN, N=100000, E=1600000, F: 512 -> 128 -> 16, fp32.
// Pipeline: deg -> dinv -> norm[e] -> h1=x@W1 -> agg1(atomic scatter) ->
//           h1r=relu(agg1+dinv^2*h1+b1) -> h2=h1r@W2 -> agg2 -> log_softmax.
// Self-loops folded into epilogues (h[i]*dinv[i]^2), never atomically added.

#define F_IN 512
#define F_HID 128
#define F_OUT 16

__global__ __launch_bounds__(256) void k_deg(const int* __restrict__ dst,
                                             const float* __restrict__ ew,
                                             float* __restrict__ deg, int E) {
  int e = blockIdx.x * 256 + threadIdx.x;
  if (e < E) atomicAdd(&deg[dst[e]], ew[e]);
}

__global__ __launch_bounds__(256) void k_dinv(float* __restrict__ deg, int n) {
  int i = blockIdx.x * 256 + threadIdx.x;
  if (i < n) {
    float d = deg[i] + 1.0f;  // +1 = self-loop weight
    deg[i] = d > 0.f ? rsqrtf(d) : 0.f;
  }
}

__global__ __launch_bounds__(256) void k_norm(const int* __restrict__ src,
                                              const int* __restrict__ dst,
                                              const float* __restrict__ ew,
                                              const float* __restrict__ dinv,
                                              float* __restrict__ nrm, int E) {
  int e = blockIdx.x * 256 + threadIdx.x;
  if (e < E) nrm[e] = dinv[src[e]] * ew[e] * dinv[dst[e]];
}

// C[n,128] = A[n,512] @ B[512,128]; fp32, 64x128 tile, 4x8 register block.
// As stored transposed [k][m] (pad 68 -> 16B-aligned rows, 2-way-max bank use)
// so inner loop is 3x ds_read_b128 per kk vs 32 FMAs.
__global__ __launch_bounds__(256) void k_gemm1(const float* __restrict__ A,
                                               const float* __restrict__ B,
                                               float* __restrict__ C, int n) {
  __shared__ float As[16][68];   // [k][m], 64 used + 4 pad
  __shared__ float Bs[16][128];  // [k][n]
  const int tid = threadIdx.x;
  const int bm = blockIdx.x * 64;
  const int ty = tid >> 4;          // 0..15 -> 4 rows each
  const int tx = tid & 15;          // 0..15 -> cols {tx*4..+3} u {64+tx*4..+3}
  const int am = tid >> 2, ak = (tid & 3) << 2;
  const int bk = tid >> 4, bx = tid & 15;
  float acc[4][8];
#pragma unroll
  for (int i = 0; i < 4; ++i)
#pragma unroll
    for (int j = 0; j < 8; ++j) acc[i][j] = 0.f;

  for (int k0 = 0; k0 < F_IN; k0 += 16) {
    float4 av = make_float4(0.f, 0.f, 0.f, 0.f);
    if (bm + am < n)
      av = *reinterpret_cast<const float4*>(&A[(size_t)(bm + am) * F_IN + k0 + ak]);
    float4 b0 = *reinterpret_cast<const float4*>(&B[(size_t)(k0 + bk) * F_HID + bx * 4]);
    float4 b1 = *reinterpret_cast<const float4*>(&B[(size_t)(k0 + bk) * F_HID + 64 + bx * 4]);
    __syncthreads();  // WAR: previous iter's reads complete before overwrite
    As[ak + 0][am] = av.x;
    As[ak + 1][am] = av.y;
    As[ak + 2][am] = av.z;
    As[ak + 3][am] = av.w;
    *reinterpret_cast<float4*>(&Bs[bk][bx * 4]) = b0;
    *reinterpret_cast<float4*>(&Bs[bk][64 + bx * 4]) = b1;
    __syncthreads();
#pragma unroll
    for (int kk = 0; kk < 16; ++kk) {
      float4 a4 = *reinterpret_cast<const float4*>(&As[kk][ty * 4]);
      float4 p0 = *reinterpret_cast<const float4*>(&Bs[kk][tx * 4]);
      float4 p1 = *reinterpret_cast<const float4*>(&Bs[kk][64 + tx * 4]);
      float a[4] = {a4.x, a4.y, a4.z, a4.w};
      float b[8] = {p0.x, p0.y, p0.z, p0.w, p1.x, p1.y, p1.z, p1.w};
#pragma unroll
      for (int i = 0; i < 4; ++i)
#pragma unroll
        for (int j = 0; j < 8; ++j) acc[i][j] = fmaf(a[i], b[j], acc[i][j]);
    }
  }
#pragma unroll
  for (int i = 0; i < 4; ++i) {
    int r = bm + ty * 4 + i;
    if (r < n) {
      *reinterpret_cast<float4*>(&C[(size_t)r * F_HID + tx * 4]) =
          make_float4(acc[i][0], acc[i][1], acc[i][2], acc[i][3]);
      *reinterpret_cast<float4*>(&C[(size_t)r * F_HID + 64 + tx * 4]) =
          make_float4(acc[i][4], acc[i][5], acc[i][6], acc[i][7]);
    }
  }
}

// Scatter-add: out[dst] += h[src] * nrm, F/4 lanes per edge, float4 gather.
template <int F>
__global__ __launch_bounds__(256) void k_agg(const int* __restrict__ src,
                                             const int* __restrict__ dst,
                                             const float* __restrict__ nrm,
                                             const float* __restrict__ h,
                                             float* __restrict__ out, int E) {
  constexpr int LPE = F / 4;
  int t = blockIdx.x * 256 + threadIdx.x;
  int e = t / LPE;
  if (e >= E) return;
  int l = t - e * LPE;
  float nm = nrm[e];
  int s = src[e];
  int d = dst[e];
  float4 v = *reinterpret_cast<const float4*>(&h[(size_t)s * F + l * 4]);
  float* o = &out[(size_t)d * F + l * 4];
  atomicAdd(o + 0, v.x * nm);
  atomicAdd(o + 1, v.y * nm);
  atomicAdd(o + 2, v.z * nm);
  atomicAdd(o + 3, v.w * nm);
}

// agg <- relu(agg + dinv[i]^2 * h + b)   (layer-1 epilogue, in place)
__global__ __launch_bounds__(256) void k_epi1(float* __restrict__ agg,
                                              const float* __restrict__ h,
                                              const float* __restrict__ dinv,
                                              const float* __restrict__ b, int n) {
  int t = blockIdx.x * 256 + threadIdx.x;
  if (t >= n * (F_HID / 4)) return;
  int i = t >> 5;   // / (F_HID/4)
  int c = t & 31;
  float di = dinv[i];
  float sl = di * di;
  float4 a = reinterpret_cast<float4*>(agg)[t];
  float4 hv = reinterpret_cast<const float4*>(h)[t];
  float4 bv = reinterpret_cast<const float4*>(b)[c];
  float4 r;
  r.x = fmaxf(fmaf(hv.x, sl, a.x) + bv.x, 0.f);
  r.y = fmaxf(fmaf(hv.y, sl, a.y) + bv.y, 0.f);
  r.z = fmaxf(fmaf(hv.z, sl, a.z) + bv.z, 0.f);
  r.w = fmaxf(fmaf(hv.w, sl, a.w) + bv.w, 0.f);
  reinterpret_cast<float4*>(agg)[t] = r;
}

// out[n,16] = h[n,128] @ W2[128,16]; W2 in LDS, 16 threads per row.
__global__ __launch_bounds__(256) void k_gemm2(const float* __restrict__ h,
                                               const float* __restrict__ W2,
                                               float* __restrict__ out, int n) {
  __shared__ float w2s[F_HID * F_OUT];
  for (int t = threadIdx.x; t < F_HID * F_OUT; t += 256) w2s[t] = W2[t];
  __syncthreads();
  int t = blockIdx.x * 256 + threadIdx.x;
  int i = t >> 4, j = t & 15;
  if (i >= n) return;
  const float4* row = reinterpret_cast<const float4*>(&h[(size_t)i * F_HID]);
  float acc = 0.f;
#pragma unroll
  for (int k4 = 0; k4 < F_HID / 4; ++k4) {
    float4 r = row[k4];
    acc = fmaf(r.x, w2s[(k4 * 4 + 0) * F_OUT + j], acc);
    acc = fmaf(r.y, w2s[(k4 * 4 + 1) * F_OUT + j], acc);
    acc = fmaf(r.z, w2s[(k4 * 4 + 2) * F_OUT + j], acc);
    acc = fmaf(r.w, w2s[(k4 * 4 + 3) * F_OUT + j], acc);
  }
  out[t] = acc;
}

// logits = agg2 + dinv^2*h2 + b2; out = log_softmax(logits) per row of 16.
__global__ __launch_bounds__(256) void k_out(const float* __restrict__ agg2,
                                             const float* __restrict__ h2,
                                             const float* __restrict__ dinv,
                                             const float* __restrict__ b2,
                                             float* __restrict__ out, int n) {
  int i = blockIdx.x * 256 + threadIdx.x;
  if (i >= n) return;
  float di = dinv[i], sl = di * di;
  const float4* a4 = reinterpret_cast<const float4*>(&agg2[(size_t)i * F_OUT]);
  const float4* h4 = reinterpret_cast<const float4*>(&h2[(size_t)i * F_OUT]);
  const float4* b4 = reinterpret_cast<const float4*>(b2);
  float v[F_OUT];
  float m = -1e30f;
#pragma unroll
  for (int q = 0; q < 4; ++q) {
    float4 a = a4[q], hh = h4[q], bb = b4[q];
    v[q * 4 + 0] = fmaf(hh.x, sl, a.x) + bb.x;
    v[q * 4 + 1] = fmaf(hh.y, sl, a.y) + bb.y;
    v[q * 4 + 2] = fmaf(hh.z, sl, a.z) + bb.z;
    v[q * 4 + 3] = fmaf(hh.w, sl, a.w) + bb.w;
  }
#pragma unroll
  for (int j = 0; j < F_OUT; ++j) m = fmaxf(m, v[j]);
  float s = 0.f;
#pragma unroll
  for (int j = 0; j < F_OUT; ++j) s += expf(v[j] - m);
  float lg = logf(s) + m;
  float4* o4 = reinterpret_cast<float4*>(&out[(size_t)i * F_OUT]);
#pragma unroll
  for (int q = 0; q < 4; ++q)
    o4[q] = make_float4(v[q * 4 + 0] - lg, v[q * 4 + 1] - lg,
                        v[q * 4 + 2] - lg, v[q * 4 + 3] - lg);
}

extern "C" void kernel_launch(void* const* d_in, const int* in_sizes, int n_in,
                              void* d_out, int out_size, void* d_ws, size_t ws_size,
                              hipStream_t stream) {
  const float* x  = (const float*)d_in[0];
  const int*   ei = (const int*)d_in[1];
  const float* ew = (const float*)d_in[2];
  const float* W1 = (const float*)d_in[3];
  const float* b1 = (const float*)d_in[4];
  const float* W2 = (const float*)d_in[5];
  const float* b2 = (const float*)d_in[6];
  float* out = (float*)d_out;

  const int fhid = in_sizes[4];         // 128
  const int fin  = in_sizes[3] / fhid;  // 512
  const int n = in_sizes[0] / fin;      // 100000
  const int E = in_sizes[2];            // 1600000
  const int* src = ei;
  const int* dst = ei + E;

  // workspace layout (floats): dinv | h1 | agg1 | h2 | agg2 | nrm  (~122 MB)
  float* ws   = (float*)d_ws;
  float* dinv = ws;
  float* h1   = ws + ((n + 255) & ~255);
  float* agg1 = h1 + (size_t)n * F_HID;
  float* h2   = agg1 + (size_t)n * F_HID;
  float* agg2 = h2 + (size_t)n * F_OUT;
  float* nrm  = agg2 + (size_t)n * F_OUT;

  hipMemsetAsync(dinv, 0, (size_t)n * 4, stream);
  hipMemsetAsync(agg1, 0, (size_t)n * F_HID * 4, stream);
  hipMemsetAsync(agg2, 0, (size_t)n * F_OUT * 4, stream);

  int gE = (E + 255) / 256;
  int gN = (n + 255) / 256;
  k_deg<<<gE, 256, 0, stream>>>(dst, ew, dinv, E);
  k_dinv<<<gN, 256, 0, stream>>>(dinv, n);
  k_norm<<<gE, 256, 0, stream>>>(src, dst, ew, dinv, nrm, E);
  k_gemm1<<<(n + 63) / 64, 256, 0, stream>>>(x, W1, h1, n);
  k_agg<F_HID><<<(E * (F_HID / 4) + 255) / 256, 256, 0, stream>>>(src, dst, nrm, h1, agg1, E);
  k_epi1<<<(n * (F_HID / 4) + 255) / 256, 256, 0, stream>>>(agg1, h1, dinv, b1, n);
  k_gemm2<<<(n * F_OUT + 255) / 256, 256, 0, stream>>>(agg1, W2, h2, n);
  k_agg<F_OUT><<<(E * (F_OUT / 4) + 255) / 256, 256, 0, stream>>>(src, dst, nrm, h2, agg2, E);
  k_out<<<gN, 256, 0, stream>>>(agg2, h2, dinv, b2, out, n);
}

// Round 2
// 1071.302 us; speedup vs baseline: 3.3158x; 3.3158x over previous
//
#include <hip/hip_runtime.h>
#include <math.h>

// 2-layer GCN, N=100000, E=1600000, F: 512 -> 128 -> 16, fp32.
// Round 2: CSR-by-dst (count/scan/scatter) + pull aggregation (no atomics in
// the hot loop). Layer-1 epilogue fused into pull128; layer-2 pull fused with
// self-loop + bias + log_softmax.

#define F_IN 512
#define F_HID 128
#define F_OUT 16

// histogram counts (int) + weighted degree (float), both by dst
__global__ __launch_bounds__(256) void k_cnt_deg(const int* __restrict__ dst,
                                                 const float* __restrict__ ew,
                                                 int* __restrict__ cnt,
                                                 float* __restrict__ degw, int E) {
  int e = blockIdx.x * 256 + threadIdx.x;
  if (e < E) {
    int d = dst[e];
    atomicAdd(&cnt[d], 1);
    atomicAdd(&degw[d], ew[e]);
  }
}

// in-place: degw -> dinv = rsqrt(degw + 1)   (+1 = self-loop weight)
__global__ __launch_bounds__(256) void k_dinv(float* __restrict__ deg, int n) {
  int i = blockIdx.x * 256 + threadIdx.x;
  if (i < n) {
    float d = deg[i] + 1.0f;
    deg[i] = d > 0.f ? rsqrtf(d) : 0.f;
  }
}

// single-block exclusive scan: cnt[n] -> rowptr[n+1]; cnt becomes the running
// cursor array (cnt[i] overwritten with exclusive prefix, reused by k_scatter).
__global__ __launch_bounds__(1024) void k_scan(int* __restrict__ cnt,
                                               int* __restrict__ rowptr, int n) {
  __shared__ int part[1024];
  const int t = threadIdx.x;
  const int chunk = (n + 1023) / 1024;
  const int lo = min(t * chunk, n), hi = min(lo + chunk, n);
  int s = 0;
  for (int i = lo; i < hi; ++i) s += cnt[i];
  part[t] = s;
  __syncthreads();
  // inclusive Hillis-Steele over 1024 partials
  for (int off = 1; off < 1024; off <<= 1) {
    int v = part[t];
    int o = (t >= off) ? part[t - off] : 0;
    __syncthreads();
    part[t] = v + o;
    __syncthreads();
  }
  int running = (t > 0) ? part[t - 1] : 0;  // exclusive prefix of this chunk
  for (int i = lo; i < hi; ++i) {
    int c = cnt[i];
    rowptr[i] = running;
    cnt[i] = running;  // cursor init
    running += c;
  }
  if (t == 1023) rowptr[n] = part[1023];
}

// scatter edges into CSR order; compute norm inline
__global__ __launch_bounds__(256) void k_scatter(const int* __restrict__ src,
                                                 const int* __restrict__ dst,
                                                 const float* __restrict__ ew,
                                                 const float* __restrict__ dinv,
                                                 int* __restrict__ cursor,
                                                 int* __restrict__ es,
                                                 float* __restrict__ en, int E) {
  int e = blockIdx.x * 256 + threadIdx.x;
  if (e >= E) return;
  int s = src[e], d = dst[e];
  int pos = atomicAdd(&cursor[d], 1);
  es[pos] = s;
  en[pos] = dinv[s] * ew[e] * dinv[d];
}

// C[n,128] = A[n,512] @ B[512,128]; fp32, 64x128 tile, 4x8 register block.
__global__ __launch_bounds__(256) void k_gemm1(const float* __restrict__ A,
                                               const float* __restrict__ B,
                                               float* __restrict__ C, int n) {
  __shared__ float As[16][68];   // [k][m], 64 used + 4 pad
  __shared__ float Bs[16][128];  // [k][n]
  const int tid = threadIdx.x;
  const int bm = blockIdx.x * 64;
  const int ty = tid >> 4;
  const int tx = tid & 15;
  const int am = tid >> 2, ak = (tid & 3) << 2;
  const int bk = tid >> 4, bx = tid & 15;
  float acc[4][8];
#pragma unroll
  for (int i = 0; i < 4; ++i)
#pragma unroll
    for (int j = 0; j < 8; ++j) acc[i][j] = 0.f;

  for (int k0 = 0; k0 < F_IN; k0 += 16) {
    float4 av = make_float4(0.f, 0.f, 0.f, 0.f);
    if (bm + am < n)
      av = *reinterpret_cast<const float4*>(&A[(size_t)(bm + am) * F_IN + k0 + ak]);
    float4 b0 = *reinterpret_cast<const float4*>(&B[(size_t)(k0 + bk) * F_HID + bx * 4]);
    float4 b1 = *reinterpret_cast<const float4*>(&B[(size_t)(k0 + bk) * F_HID + 64 + bx * 4]);
    __syncthreads();
    As[ak + 0][am] = av.x;
    As[ak + 1][am] = av.y;
    As[ak + 2][am] = av.z;
    As[ak + 3][am] = av.w;
    *reinterpret_cast<float4*>(&Bs[bk][bx * 4]) = b0;
    *reinterpret_cast<float4*>(&Bs[bk][64 + bx * 4]) = b1;
    __syncthreads();
#pragma unroll
    for (int kk = 0; kk < 16; ++kk) {
      float4 a4 = *reinterpret_cast<const float4*>(&As[kk][ty * 4]);
      float4 p0 = *reinterpret_cast<const float4*>(&Bs[kk][tx * 4]);
      float4 p1 = *reinterpret_cast<const float4*>(&Bs[kk][64 + tx * 4]);
      float a[4] = {a4.x, a4.y, a4.z, a4.w};
      float b[8] = {p0.x, p0.y, p0.z, p0.w, p1.x, p1.y, p1.z, p1.w};
#pragma unroll
      for (int i = 0; i < 4; ++i)
#pragma unroll
        for (int j = 0; j < 8; ++j) acc[i][j] = fmaf(a[i], b[j], acc[i][j]);
    }
  }
#pragma unroll
  for (int i = 0; i < 4; ++i) {
    int r = bm + ty * 4 + i;
    if (r < n) {
      *reinterpret_cast<float4*>(&C[(size_t)r * F_HID + tx * 4]) =
          make_float4(acc[i][0], acc[i][1], acc[i][2], acc[i][3]);
      *reinterpret_cast<float4*>(&C[(size_t)r * F_HID + 64 + tx * 4]) =
          make_float4(acc[i][4], acc[i][5], acc[i][6], acc[i][7]);
    }
  }
}

// pull-aggregate layer 1: one wave per node, float2 per lane (128 cols).
// out = relu(sum_j nrm_j * h1[src_j] + dinv^2 * h1[node] + b1)
__global__ __launch_bounds__(256) void k_pull128(const int* __restrict__ rowptr,
                                                 const int* __restrict__ es,
                                                 const float* __restrict__ en,
                                                 const float* __restrict__ h1,
                                                 const float* __restrict__ dinv,
                                                 const float* __restrict__ b1,
                                                 float* __restrict__ out, int n) {
  int node = blockIdx.x * 4 + (threadIdx.x >> 6);
  if (node >= n) return;
  int lane = threadIdx.x & 63;
  int beg = rowptr[node], end = rowptr[node + 1];
  float ax = 0.f, ay = 0.f;
  int j = beg;
  for (; j + 1 < end; j += 2) {
    int s0 = es[j], s1 = es[j + 1];
    float n0 = en[j], n1 = en[j + 1];
    float2 v0 = *reinterpret_cast<const float2*>(&h1[(size_t)s0 * F_HID + lane * 2]);
    float2 v1 = *reinterpret_cast<const float2*>(&h1[(size_t)s1 * F_HID + lane * 2]);
    ax = fmaf(v0.x, n0, ax);
    ay = fmaf(v0.y, n0, ay);
    ax = fmaf(v1.x, n1, ax);
    ay = fmaf(v1.y, n1, ay);
  }
  if (j < end) {
    int s0 = es[j];
    float n0 = en[j];
    float2 v0 = *reinterpret_cast<const float2*>(&h1[(size_t)s0 * F_HID + lane * 2]);
    ax = fmaf(v0.x, n0, ax);
    ay = fmaf(v0.y, n0, ay);
  }
  float di = dinv[node], sl = di * di;
  float2 hv = *reinterpret_cast<const float2*>(&h1[(size_t)node * F_HID + lane * 2]);
  float2 bv = *reinterpret_cast<const float2*>(&b1[lane * 2]);
  float2 r;
  r.x = fmaxf(fmaf(hv.x, sl, ax) + bv.x, 0.f);
  r.y = fmaxf(fmaf(hv.y, sl, ay) + bv.y, 0.f);
  *reinterpret_cast<float2*>(&out[(size_t)node * F_HID + lane * 2]) = r;
}

// out[n,16] = h[n,128] @ W2[128,16]; W2 in LDS, 16 threads per row.
__global__ __launch_bounds__(256) void k_gemm2(const float* __restrict__ h,
                                               const float* __restrict__ W2,
                                               float* __restrict__ out, int n) {
  __shared__ float w2s[F_HID * F_OUT];
  for (int t = threadIdx.x; t < F_HID * F_OUT; t += 256) w2s[t] = W2[t];
  __syncthreads();
  int t = blockIdx.x * 256 + threadIdx.x;
  int i = t >> 4, j = t & 15;
  if (i >= n) return;
  const float4* row = reinterpret_cast<const float4*>(&h[(size_t)i * F_HID]);
  float acc = 0.f;
#pragma unroll
  for (int k4 = 0; k4 < F_HID / 4; ++k4) {
    float4 r = row[k4];
    acc = fmaf(r.x, w2s[(k4 * 4 + 0) * F_OUT + j], acc);
    acc = fmaf(r.y, w2s[(k4 * 4 + 1) * F_OUT + j], acc);
    acc = fmaf(r.z, w2s[(k4 * 4 + 2) * F_OUT + j], acc);
    acc = fmaf(r.w, w2s[(k4 * 4 + 3) * F_OUT + j], acc);
  }
  out[t] = acc;
}

// pull-aggregate layer 2 (16 cols, 16 lanes/node) + self-loop + bias +
// log_softmax over the 16-lane group.
__global__ __launch_bounds__(256) void k_pull16_out(const int* __restrict__ rowptr,
                                                    const int* __restrict__ es,
                                                    const float* __restrict__ en,
                                                    const float* __restrict__ h2,
                                                    const float* __restrict__ dinv,
                                                    const float* __restrict__ b2,
                                                    float* __restrict__ out, int n) {
  int node = blockIdx.x * 16 + (threadIdx.x >> 4);
  if (node >= n) return;
  int lane = threadIdx.x & 15;
  int beg = rowptr[node], end = rowptr[node + 1];
  float acc = 0.f;
  int j = beg;
  for (; j + 1 < end; j += 2) {
    float v0 = h2[(size_t)es[j] * F_OUT + lane];
    float v1 = h2[(size_t)es[j + 1] * F_OUT + lane];
    acc = fmaf(v0, en[j], acc);
    acc = fmaf(v1, en[j + 1], acc);
  }
  if (j < end) acc = fmaf(h2[(size_t)es[j] * F_OUT + lane], en[j], acc);
  float di = dinv[node];
  float v = fmaf(h2[(size_t)node * F_OUT + lane], di * di, acc) + b2[lane];
  float m = v;
#pragma unroll
  for (int off = 8; off; off >>= 1) m = fmaxf(m, __shfl_xor(m, off, 16));
  float ex = expf(v - m);
  float s = ex;
#pragma unroll
  for (int off = 8; off; off >>= 1) s += __shfl_xor(s, off, 16);
  out[(size_t)node * F_OUT + lane] = v - m - logf(s);
}

extern "C" void kernel_launch(void* const* d_in, const int* in_sizes, int n_in,
                              void* d_out, int out_size, void* d_ws, size_t ws_size,
                              hipStream_t stream) {
  const float* x  = (const float*)d_in[0];
  const int*   ei = (const int*)d_in[1];
  const float* ew = (const float*)d_in[2];
  const float* W1 = (const float*)d_in[3];
  const float* b1 = (const float*)d_in[4];
  const float* W2 = (const float*)d_in[5];
  const float* b2 = (const float*)d_in[6];
  float* out = (float*)d_out;

  const int fhid = in_sizes[4];         // 128
  const int fin  = in_sizes[3] / fhid;  // 512
  const int n = in_sizes[0] / fin;      // 100000
  const int E = in_sizes[2];            // 1600000
  const int* src = ei;
  const int* dst = ei + E;

  // workspace (4B units): dinv | h1 | agg1 | h2 | cnt/cursor | rowptr | es | en
  const size_t nr = (size_t)((n + 255) & ~255);
  float* ws     = (float*)d_ws;
  float* dinv   = ws;                       // [nr] (degw then dinv, in place)
  float* h1     = dinv + nr;                // [n*128]
  float* agg1   = h1 + (size_t)n * F_HID;   // [n*128]
  float* h2     = agg1 + (size_t)n * F_HID; // [n*16]
  int*   cnt    = (int*)(h2 + (size_t)n * F_OUT);  // [nr] counts -> cursor
  int*   rowptr = cnt + nr;                 // [n+1]
  int*   es     = rowptr + nr;              // [E]
  float* en     = (float*)(es + E);         // [E]

  hipMemsetAsync(dinv, 0, nr * 4, stream);
  hipMemsetAsync(cnt, 0, nr * 4, stream);

  int gE = (E + 255) / 256;
  int gN = (n + 255) / 256;
  k_cnt_deg<<<gE, 256, 0, stream>>>(dst, ew, cnt, dinv, E);
  k_dinv<<<gN, 256, 0, stream>>>(dinv, n);
  k_scan<<<1, 1024, 0, stream>>>(cnt, rowptr, n);
  k_scatter<<<gE, 256, 0, stream>>>(src, dst, ew, dinv, cnt, es, en, E);
  k_gemm1<<<(n + 63) / 64, 256, 0, stream>>>(x, W1, h1, n);
  k_pull128<<<(n + 3) / 4, 256, 0, stream>>>(rowptr, es, en, h1, dinv, b1, agg1, n);
  k_gemm2<<<(n * F_OUT + 255) / 256, 256, 0, stream>>>(agg1, W2, h2, n);
  k_pull16_out<<<(n + 15) / 16, 256, 0, stream>>>(rowptr, es, en, h2, dinv, b2, out, n);
}

// Round 3
// 865.339 us; speedup vs baseline: 4.1050x; 1.2380x over previous
//
#include <hip/hip_runtime.h>
#include <math.h>

// 2-layer GCN, N=100000, E=1600000, F: 512 -> 128 -> 16, fp32.
// Round 3: replace single-block scan (228us, 1 CU) with 3-pass multi-block
// scan (~10us). Rest unchanged from round 2 (CSR pull, fused epilogues).

#define F_IN 512
#define F_HID 128
#define F_OUT 16

// histogram counts (int) + weighted degree (float), both by dst
__global__ __launch_bounds__(256) void k_cnt_deg(const int* __restrict__ dst,
                                                 const float* __restrict__ ew,
                                                 int* __restrict__ cnt,
                                                 float* __restrict__ degw, int E) {
  int e = blockIdx.x * 256 + threadIdx.x;
  if (e < E) {
    int d = dst[e];
    atomicAdd(&cnt[d], 1);
    atomicAdd(&degw[d], ew[e]);
  }
}

// in-place: degw -> dinv = rsqrt(degw + 1)   (+1 = self-loop weight)
__global__ __launch_bounds__(256) void k_dinv(float* __restrict__ deg, int n) {
  int i = blockIdx.x * 256 + threadIdx.x;
  if (i < n) {
    float d = deg[i] + 1.0f;
    deg[i] = d > 0.f ? rsqrtf(d) : 0.f;
  }
}

// ---- 3-pass scan: cnt[n] -> rowptr (exclusive), bsum = per-block totals ----
__global__ __launch_bounds__(256) void k_scan1(const int* __restrict__ cnt,
                                               int* __restrict__ rowptr,
                                               int* __restrict__ bsum, int n) {
  __shared__ int sd[256];
  const int t = threadIdx.x;
  const int i = blockIdx.x * 256 + t;
  int v = (i < n) ? cnt[i] : 0;
  sd[t] = v;
  __syncthreads();
#pragma unroll
  for (int off = 1; off < 256; off <<= 1) {
    int add = (t >= off) ? sd[t - off] : 0;
    __syncthreads();
    sd[t] += add;
    __syncthreads();
  }
  if (i < n) rowptr[i] = sd[t] - v;  // exclusive, pre-offset
  if (t == 255) bsum[blockIdx.x] = sd[255];
}

// single block scans <=512 block sums in place (inclusive -> exclusive)
__global__ __launch_bounds__(512) void k_scan2(int* __restrict__ bsum, int nb) {
  __shared__ int sd[512];
  const int t = threadIdx.x;
  int v = (t < nb) ? bsum[t] : 0;
  sd[t] = v;
  __syncthreads();
#pragma unroll
  for (int off = 1; off < 512; off <<= 1) {
    int add = (t >= off) ? sd[t - off] : 0;
    __syncthreads();
    sd[t] += add;
    __syncthreads();
  }
  if (t < nb) bsum[t] = sd[t] - v;  // exclusive
}

// add block offsets; init cursor; write rowptr[n] = E (total = E by constr.)
__global__ __launch_bounds__(256) void k_scan3(int* __restrict__ rowptr,
                                               const int* __restrict__ bsum,
                                               int* __restrict__ cursor,
                                               int n, int E) {
  int i = blockIdx.x * 256 + threadIdx.x;
  if (i < n) {
    int r = rowptr[i] + bsum[blockIdx.x];
    rowptr[i] = r;
    cursor[i] = r;
  }
  if (i == 0) rowptr[n] = E;
}

// scatter edges into CSR order; compute norm inline
__global__ __launch_bounds__(256) void k_scatter(const int* __restrict__ src,
                                                 const int* __restrict__ dst,
                                                 const float* __restrict__ ew,
                                                 const float* __restrict__ dinv,
                                                 int* __restrict__ cursor,
                                                 int* __restrict__ es,
                                                 float* __restrict__ en, int E) {
  int e = blockIdx.x * 256 + threadIdx.x;
  if (e >= E) return;
  int s = src[e], d = dst[e];
  int pos = atomicAdd(&cursor[d], 1);
  es[pos] = s;
  en[pos] = dinv[s] * ew[e] * dinv[d];
}

// C[n,128] = A[n,512] @ B[512,128]; fp32, 64x128 tile, 4x8 register block.
__global__ __launch_bounds__(256) void k_gemm1(const float* __restrict__ A,
                                               const float* __restrict__ B,
                                               float* __restrict__ C, int n) {
  __shared__ float As[16][68];   // [k][m], 64 used + 4 pad
  __shared__ float Bs[16][128];  // [k][n]
  const int tid = threadIdx.x;
  const int bm = blockIdx.x * 64;
  const int ty = tid >> 4;
  const int tx = tid & 15;
  const int am = tid >> 2, ak = (tid & 3) << 2;
  const int bk = tid >> 4, bx = tid & 15;
  float acc[4][8];
#pragma unroll
  for (int i = 0; i < 4; ++i)
#pragma unroll
    for (int j = 0; j < 8; ++j) acc[i][j] = 0.f;

  for (int k0 = 0; k0 < F_IN; k0 += 16) {
    float4 av = make_float4(0.f, 0.f, 0.f, 0.f);
    if (bm + am < n)
      av = *reinterpret_cast<const float4*>(&A[(size_t)(bm + am) * F_IN + k0 + ak]);
    float4 b0 = *reinterpret_cast<const float4*>(&B[(size_t)(k0 + bk) * F_HID + bx * 4]);
    float4 b1 = *reinterpret_cast<const float4*>(&B[(size_t)(k0 + bk) * F_HID + 64 + bx * 4]);
    __syncthreads();
    As[ak + 0][am] = av.x;
    As[ak + 1][am] = av.y;
    As[ak + 2][am] = av.z;
    As[ak + 3][am] = av.w;
    *reinterpret_cast<float4*>(&Bs[bk][bx * 4]) = b0;
    *reinterpret_cast<float4*>(&Bs[bk][64 + bx * 4]) = b1;
    __syncthreads();
#pragma unroll
    for (int kk = 0; kk < 16; ++kk) {
      float4 a4 = *reinterpret_cast<const float4*>(&As[kk][ty * 4]);
      float4 p0 = *reinterpret_cast<const float4*>(&Bs[kk][tx * 4]);
      float4 p1 = *reinterpret_cast<const float4*>(&Bs[kk][64 + tx * 4]);
      float a[4] = {a4.x, a4.y, a4.z, a4.w};
      float b[8] = {p0.x, p0.y, p0.z, p0.w, p1.x, p1.y, p1.z, p1.w};
#pragma unroll
      for (int i = 0; i < 4; ++i)
#pragma unroll
        for (int j = 0; j < 8; ++j) acc[i][j] = fmaf(a[i], b[j], acc[i][j]);
    }
  }
#pragma unroll
  for (int i = 0; i < 4; ++i) {
    int r = bm + ty * 4 + i;
    if (r < n) {
      *reinterpret_cast<float4*>(&C[(size_t)r * F_HID + tx * 4]) =
          make_float4(acc[i][0], acc[i][1], acc[i][2], acc[i][3]);
      *reinterpret_cast<float4*>(&C[(size_t)r * F_HID + 64 + tx * 4]) =
          make_float4(acc[i][4], acc[i][5], acc[i][6], acc[i][7]);
    }
  }
}

// pull-aggregate layer 1: one wave per node, float2 per lane (128 cols).
// out = relu(sum_j nrm_j * h1[src_j] + dinv^2 * h1[node] + b1)
__global__ __launch_bounds__(256) void k_pull128(const int* __restrict__ rowptr,
                                                 const int* __restrict__ es,
                                                 const float* __restrict__ en,
                                                 const float* __restrict__ h1,
                                                 const float* __restrict__ dinv,
                                                 const float* __restrict__ b1,
                                                 float* __restrict__ out, int n) {
  int node = blockIdx.x * 4 + (threadIdx.x >> 6);
  if (node >= n) return;
  int lane = threadIdx.x & 63;
  int beg = rowptr[node], end = rowptr[node + 1];
  float ax = 0.f, ay = 0.f;
  int j = beg;
  for (; j + 1 < end; j += 2) {
    int s0 = es[j], s1 = es[j + 1];
    float n0 = en[j], n1 = en[j + 1];
    float2 v0 = *reinterpret_cast<const float2*>(&h1[(size_t)s0 * F_HID + lane * 2]);
    float2 v1 = *reinterpret_cast<const float2*>(&h1[(size_t)s1 * F_HID + lane * 2]);
    ax = fmaf(v0.x, n0, ax);
    ay = fmaf(v0.y, n0, ay);
    ax = fmaf(v1.x, n1, ax);
    ay = fmaf(v1.y, n1, ay);
  }
  if (j < end) {
    int s0 = es[j];
    float n0 = en[j];
    float2 v0 = *reinterpret_cast<const float2*>(&h1[(size_t)s0 * F_HID + lane * 2]);
    ax = fmaf(v0.x, n0, ax);
    ay = fmaf(v0.y, n0, ay);
  }
  float di = dinv[node], sl = di * di;
  float2 hv = *reinterpret_cast<const float2*>(&h1[(size_t)node * F_HID + lane * 2]);
  float2 bv = *reinterpret_cast<const float2*>(&b1[lane * 2]);
  float2 r;
  r.x = fmaxf(fmaf(hv.x, sl, ax) + bv.x, 0.f);
  r.y = fmaxf(fmaf(hv.y, sl, ay) + bv.y, 0.f);
  *reinterpret_cast<float2*>(&out[(size_t)node * F_HID + lane * 2]) = r;
}

// out[n,16] = h[n,128] @ W2[128,16]; W2 in LDS, 16 threads per row.
__global__ __launch_bounds__(256) void k_gemm2(const float* __restrict__ h,
                                               const float* __restrict__ W2,
                                               float* __restrict__ out, int n) {
  __shared__ float w2s[F_HID * F_OUT];
  for (int t = threadIdx.x; t < F_HID * F_OUT; t += 256) w2s[t] = W2[t];
  __syncthreads();
  int t = blockIdx.x * 256 + threadIdx.x;
  int i = t >> 4, j = t & 15;
  if (i >= n) return;
  const float4* row = reinterpret_cast<const float4*>(&h[(size_t)i * F_HID]);
  float acc = 0.f;
#pragma unroll
  for (int k4 = 0; k4 < F_HID / 4; ++k4) {
    float4 r = row[k4];
    acc = fmaf(r.x, w2s[(k4 * 4 + 0) * F_OUT + j], acc);
    acc = fmaf(r.y, w2s[(k4 * 4 + 1) * F_OUT + j], acc);
    acc = fmaf(r.z, w2s[(k4 * 4 + 2) * F_OUT + j], acc);
    acc = fmaf(r.w, w2s[(k4 * 4 + 3) * F_OUT + j], acc);
  }
  out[t] = acc;
}

// pull-aggregate layer 2 (16 cols, 16 lanes/node) + self-loop + bias +
// log_softmax over the 16-lane group.
__global__ __launch_bounds__(256) void k_pull16_out(const int* __restrict__ rowptr,
                                                    const int* __restrict__ es,
                                                    const float* __restrict__ en,
                                                    const float* __restrict__ h2,
                                                    const float* __restrict__ dinv,
                                                    const float* __restrict__ b2,
                                                    float* __restrict__ out, int n) {
  int node = blockIdx.x * 16 + (threadIdx.x >> 4);
  if (node >= n) return;
  int lane = threadIdx.x & 15;
  int beg = rowptr[node], end = rowptr[node + 1];
  float acc = 0.f;
  int j = beg;
  for (; j + 1 < end; j += 2) {
    float v0 = h2[(size_t)es[j] * F_OUT + lane];
    float v1 = h2[(size_t)es[j + 1] * F_OUT + lane];
    acc = fmaf(v0, en[j], acc);
    acc = fmaf(v1, en[j + 1], acc);
  }
  if (j < end) acc = fmaf(h2[(size_t)es[j] * F_OUT + lane], en[j], acc);
  float di = dinv[node];
  float v = fmaf(h2[(size_t)node * F_OUT + lane], di * di, acc) + b2[lane];
  float m = v;
#pragma unroll
  for (int off = 8; off; off >>= 1) m = fmaxf(m, __shfl_xor(m, off, 16));
  float ex = expf(v - m);
  float s = ex;
#pragma unroll
  for (int off = 8; off; off >>= 1) s += __shfl_xor(s, off, 16);
  out[(size_t)node * F_OUT + lane] = v - m - logf(s);
}

extern "C" void kernel_launch(void* const* d_in, const int* in_sizes, int n_in,
                              void* d_out, int out_size, void* d_ws, size_t ws_size,
                              hipStream_t stream) {
  const float* x  = (const float*)d_in[0];
  const int*   ei = (const int*)d_in[1];
  const float* ew = (const float*)d_in[2];
  const float* W1 = (const float*)d_in[3];
  const float* b1 = (const float*)d_in[4];
  const float* W2 = (const float*)d_in[5];
  const float* b2 = (const float*)d_in[6];
  float* out = (float*)d_out;

  const int fhid = in_sizes[4];         // 128
  const int fin  = in_sizes[3] / fhid;  // 512
  const int n = in_sizes[0] / fin;      // 100000
  const int E = in_sizes[2];            // 1600000
  const int* src = ei;
  const int* dst = ei + E;

  // workspace (4B units): dinv | h1 | agg1 | h2 | cnt/cursor | rowptr | bsum | es | en
  const size_t nr = (size_t)((n + 255) & ~255);
  float* ws     = (float*)d_ws;
  float* dinv   = ws;                       // [nr] (degw then dinv, in place)
  float* h1     = dinv + nr;                // [n*128]
  float* agg1   = h1 + (size_t)n * F_HID;   // [n*128]
  float* h2     = agg1 + (size_t)n * F_HID; // [n*16]
  int*   cnt    = (int*)(h2 + (size_t)n * F_OUT);  // [nr] counts -> cursor
  int*   rowptr = cnt + nr;                 // [n+1]
  int*   bsum   = rowptr + nr;              // [512]
  int*   es     = bsum + 512;               // [E]
  float* en     = (float*)(es + E);         // [E]

  hipMemsetAsync(dinv, 0, nr * 4, stream);
  hipMemsetAsync(cnt, 0, nr * 4, stream);

  const int gE = (E + 255) / 256;
  const int gN = (n + 255) / 256;  // 391 blocks
  k_cnt_deg<<<gE, 256, 0, stream>>>(dst, ew, cnt, dinv, E);
  k_dinv<<<gN, 256, 0, stream>>>(dinv, n);
  k_scan1<<<gN, 256, 0, stream>>>(cnt, rowptr, bsum, n);
  k_scan2<<<1, 512, 0, stream>>>(bsum, gN);
  k_scan3<<<gN, 256, 0, stream>>>(rowptr, bsum, cnt, n, E);
  k_scatter<<<gE, 256, 0, stream>>>(src, dst, ew, dinv, cnt, es, en, E);
  k_gemm1<<<(n + 63) / 64, 256, 0, stream>>>(x, W1, h1, n);
  k_pull128<<<(n + 3) / 4, 256, 0, stream>>>(rowptr, es, en, h1, dinv, b1, agg1, n);
  k_gemm2<<<(n * F_OUT + 255) / 256, 256, 0, stream>>>(agg1, W2, h2, n);
  k_pull16_out<<<(n + 15) / 16, 256, 0, stream>>>(rowptr, es, en, h2, dinv, b2, out, n);
}

// Round 5
// 811.753 us; speedup vs baseline: 4.3760x; 1.0660x over previous
//
#include <hip/hip_runtime.h>
#include <math.h>

// 2-layer GCN, N=100000, E=1600000, F: 512 -> 128 -> 16, fp32.
// Round 4 (resubmit after broker timeout): GEMM1 switched from fp32 vector
// (196us, 67TF) to bf16 MFMA with in-kernel fp32->bf16 conversion
// (HBM-bound, ~45us predicted). W1 is pre-transposed/converted once (k_w1t).
// Everything else unchanged.

#define F_IN 512
#define F_HID 128
#define F_OUT 16

typedef __attribute__((ext_vector_type(8))) short bf16x8;
typedef __attribute__((ext_vector_type(4))) float f32x4;

__device__ __forceinline__ unsigned short f2bf(float f) {
  union { float f; unsigned u; } c;
  c.f = f;
  unsigned u = c.u;
  return (unsigned short)((u + 0x7FFFu + ((u >> 16) & 1u)) >> 16);
}

// histogram counts (int) + weighted degree (float), both by dst
__global__ __launch_bounds__(256) void k_cnt_deg(const int* __restrict__ dst,
                                                 const float* __restrict__ ew,
                                                 int* __restrict__ cnt,
                                                 float* __restrict__ degw, int E) {
  int e = blockIdx.x * 256 + threadIdx.x;
  if (e < E) {
    int d = dst[e];
    atomicAdd(&cnt[d], 1);
    atomicAdd(&degw[d], ew[e]);
  }
}

// in-place: degw -> dinv = rsqrt(degw + 1)   (+1 = self-loop weight)
__global__ __launch_bounds__(256) void k_dinv(float* __restrict__ deg, int n) {
  int i = blockIdx.x * 256 + threadIdx.x;
  if (i < n) {
    float d = deg[i] + 1.0f;
    deg[i] = d > 0.f ? rsqrtf(d) : 0.f;
  }
}

// ---- 3-pass scan: cnt[n] -> rowptr (exclusive), bsum = per-block totals ----
__global__ __launch_bounds__(256) void k_scan1(const int* __restrict__ cnt,
                                               int* __restrict__ rowptr,
                                               int* __restrict__ bsum, int n) {
  __shared__ int sd[256];
  const int t = threadIdx.x;
  const int i = blockIdx.x * 256 + t;
  int v = (i < n) ? cnt[i] : 0;
  sd[t] = v;
  __syncthreads();
#pragma unroll
  for (int off = 1; off < 256; off <<= 1) {
    int add = (t >= off) ? sd[t - off] : 0;
    __syncthreads();
    sd[t] += add;
    __syncthreads();
  }
  if (i < n) rowptr[i] = sd[t] - v;  // exclusive, pre-offset
  if (t == 255) bsum[blockIdx.x] = sd[255];
}

// single block scans <=512 block sums in place (inclusive -> exclusive)
__global__ __launch_bounds__(512) void k_scan2(int* __restrict__ bsum, int nb) {
  __shared__ int sd[512];
  const int t = threadIdx.x;
  int v = (t < nb) ? bsum[t] : 0;
  sd[t] = v;
  __syncthreads();
#pragma unroll
  for (int off = 1; off < 512; off <<= 1) {
    int add = (t >= off) ? sd[t - off] : 0;
    __syncthreads();
    sd[t] += add;
    __syncthreads();
  }
  if (t < nb) bsum[t] = sd[t] - v;  // exclusive
}

// add block offsets; init cursor; write rowptr[n] = E (total = E by constr.)
__global__ __launch_bounds__(256) void k_scan3(int* __restrict__ rowptr,
                                               const int* __restrict__ bsum,
                                               int* __restrict__ cursor,
                                               int n, int E) {
  int i = blockIdx.x * 256 + threadIdx.x;
  if (i < n) {
    int r = rowptr[i] + bsum[blockIdx.x];
    rowptr[i] = r;
    cursor[i] = r;
  }
  if (i == 0) rowptr[n] = E;
}

// scatter edges into CSR order; compute norm inline
__global__ __launch_bounds__(256) void k_scatter(const int* __restrict__ src,
                                                 const int* __restrict__ dst,
                                                 const float* __restrict__ ew,
                                                 const float* __restrict__ dinv,
                                                 int* __restrict__ cursor,
                                                 int* __restrict__ es,
                                                 float* __restrict__ en, int E) {
  int e = blockIdx.x * 256 + threadIdx.x;
  if (e >= E) return;
  int s = src[e], d = dst[e];
  int pos = atomicAdd(&cursor[d], 1);
  es[pos] = s;
  en[pos] = dinv[s] * ew[e] * dinv[d];
}

// one-shot: W1[512][128] fp32 -> W1T[128][512] bf16 (so B-fragments have 8
// contiguous k per lane; 128 KB, L2-resident during GEMM)
__global__ __launch_bounds__(256) void k_w1t(const float* __restrict__ W1,
                                             unsigned short* __restrict__ W1T) {
  int t = blockIdx.x * 256 + threadIdx.x;  // 65536 total
  int k = t >> 7, c = t & 127;
  W1T[(size_t)c * F_IN + k] = f2bf(W1[t]);
}

// C[n,128] = A[n,512] @ W1; bf16 MFMA 16x16x32. 256 thr = 4 waves, BM=128,
// each wave 32 rows x 128 cols (acc 2x8 f32x4). A: fp32 global -> bf16 LDS
// (double-buffered, loads issued one tile early). B: direct global bf16
// fragment loads from W1T (L1/L2-resident).
__global__ __launch_bounds__(256) void k_gemm1m(const float* __restrict__ A,
                                                const unsigned short* __restrict__ BT,
                                                float* __restrict__ C, int n) {
  __shared__ unsigned short As[2][128][72];  // 64 k + 8 pad; row = 144 B = 9x16B
  const int tid = threadIdx.x;
  const int wave = tid >> 6, lane = tid & 63;
  const int lg = lane >> 4, lr = lane & 15;
  const int bm = blockIdx.x * 128;
  const int srow = tid >> 1;            // 2 threads per row
  const int scol = (tid & 1) * 32;      // each covers 32 floats of the 64-k tile
  const bool sok = (bm + srow) < n;
  const float* abase = &A[(size_t)(bm + srow) * F_IN + scol];

  f32x4 acc[2][8];
#pragma unroll
  for (int i = 0; i < 2; ++i)
#pragma unroll
    for (int j = 0; j < 8; ++j) acc[i][j] = (f32x4){0.f, 0.f, 0.f, 0.f};

  float4 stg[8];
#define ISSUE(K0)                                                            \
  {                                                                          \
    _Pragma("unroll") for (int i = 0; i < 8; ++i)                            \
        stg[i] = sok ? *reinterpret_cast<const float4*>(abase + (K0) + i * 4)\
                     : make_float4(0.f, 0.f, 0.f, 0.f);                      \
  }
#define WRITE_LDS(BUF)                                                       \
  {                                                                          \
    _Pragma("unroll") for (int i = 0; i < 4; ++i) {                          \
      bf16x8 w;                                                              \
      w[0] = (short)f2bf(stg[2 * i].x);                                      \
      w[1] = (short)f2bf(stg[2 * i].y);                                      \
      w[2] = (short)f2bf(stg[2 * i].z);                                      \
      w[3] = (short)f2bf(stg[2 * i].w);                                      \
      w[4] = (short)f2bf(stg[2 * i + 1].x);                                  \
      w[5] = (short)f2bf(stg[2 * i + 1].y);                                  \
      w[6] = (short)f2bf(stg[2 * i + 1].z);                                  \
      w[7] = (short)f2bf(stg[2 * i + 1].w);                                  \
      *reinterpret_cast<bf16x8*>(&As[BUF][srow][scol + i * 8]) = w;          \
    }                                                                        \
  }

  ISSUE(0)
  WRITE_LDS(0)
  __syncthreads();

  for (int t = 0; t < 8; ++t) {
    const int buf = t & 1;
    if (t < 7) ISSUE((t + 1) * 64)
    const int k0 = t * 64;
#pragma unroll
    for (int s = 0; s < 2; ++s) {
      bf16x8 a0 = *reinterpret_cast<bf16x8*>(&As[buf][wave * 32 + lr][s * 32 + lg * 8]);
      bf16x8 a1 = *reinterpret_cast<bf16x8*>(&As[buf][wave * 32 + 16 + lr][s * 32 + lg * 8]);
      bf16x8 b[8];
#pragma unroll
      for (int nf = 0; nf < 8; ++nf)
        b[nf] = *reinterpret_cast<const bf16x8*>(
            &BT[(size_t)(nf * 16 + lr) * F_IN + k0 + s * 32 + lg * 8]);
#pragma unroll
      for (int nf = 0; nf < 8; ++nf) {
        acc[0][nf] = __builtin_amdgcn_mfma_f32_16x16x32_bf16(a0, b[nf], acc[0][nf], 0, 0, 0);
        acc[1][nf] = __builtin_amdgcn_mfma_f32_16x16x32_bf16(a1, b[nf], acc[1][nf], 0, 0, 0);
      }
    }
    if (t < 7) WRITE_LDS(buf ^ 1)
    __syncthreads();
  }

  // C/D layout (m89): col = lane&15, row = (lane>>4)*4 + reg
  const int rbase = bm + wave * 32 + lg * 4;
#pragma unroll
  for (int mf = 0; mf < 2; ++mf)
#pragma unroll
    for (int r = 0; r < 4; ++r) {
      int row = rbase + mf * 16 + r;
      if (row < n) {
#pragma unroll
        for (int nf = 0; nf < 8; ++nf)
          C[(size_t)row * F_HID + nf * 16 + lr] = acc[mf][nf][r];
      }
    }
#undef ISSUE
#undef WRITE_LDS
}

// pull-aggregate layer 1: one wave per node, float2 per lane (128 cols).
// out = relu(sum_j nrm_j * h1[src_j] + dinv^2 * h1[node] + b1)
__global__ __launch_bounds__(256) void k_pull128(const int* __restrict__ rowptr,
                                                 const int* __restrict__ es,
                                                 const float* __restrict__ en,
                                                 const float* __restrict__ h1,
                                                 const float* __restrict__ dinv,
                                                 const float* __restrict__ b1,
                                                 float* __restrict__ out, int n) {
  int node = blockIdx.x * 4 + (threadIdx.x >> 6);
  if (node >= n) return;
  int lane = threadIdx.x & 63;
  int beg = rowptr[node], end = rowptr[node + 1];
  float ax = 0.f, ay = 0.f;
  int j = beg;
  for (; j + 1 < end; j += 2) {
    int s0 = es[j], s1 = es[j + 1];
    float n0 = en[j], n1 = en[j + 1];
    float2 v0 = *reinterpret_cast<const float2*>(&h1[(size_t)s0 * F_HID + lane * 2]);
    float2 v1 = *reinterpret_cast<const float2*>(&h1[(size_t)s1 * F_HID + lane * 2]);
    ax = fmaf(v0.x, n0, ax);
    ay = fmaf(v0.y, n0, ay);
    ax = fmaf(v1.x, n1, ax);
    ay = fmaf(v1.y, n1, ay);
  }
  if (j < end) {
    int s0 = es[j];
    float n0 = en[j];
    float2 v0 = *reinterpret_cast<const float2*>(&h1[(size_t)s0 * F_HID + lane * 2]);
    ax = fmaf(v0.x, n0, ax);
    ay = fmaf(v0.y, n0, ay);
  }
  float di = dinv[node], sl = di * di;
  float2 hv = *reinterpret_cast<const float2*>(&h1[(size_t)node * F_HID + lane * 2]);
  float2 bv = *reinterpret_cast<const float2*>(&b1[lane * 2]);
  float2 r;
  r.x = fmaxf(fmaf(hv.x, sl, ax) + bv.x, 0.f);
  r.y = fmaxf(fmaf(hv.y, sl, ay) + bv.y, 0.f);
  *reinterpret_cast<float2*>(&out[(size_t)node * F_HID + lane * 2]) = r;
}

// out[n,16] = h[n,128] @ W2[128,16]; W2 in LDS, 16 threads per row.
__global__ __launch_bounds__(256) void k_gemm2(const float* __restrict__ h,
                                               const float* __restrict__ W2,
                                               float* __restrict__ out, int n) {
  __shared__ float w2s[F_HID * F_OUT];
  for (int t = threadIdx.x; t < F_HID * F_OUT; t += 256) w2s[t] = W2[t];
  __syncthreads();
  int t = blockIdx.x * 256 + threadIdx.x;
  int i = t >> 4, j = t & 15;
  if (i >= n) return;
  const float4* row = reinterpret_cast<const float4*>(&h[(size_t)i * F_HID]);
  float acc = 0.f;
#pragma unroll
  for (int k4 = 0; k4 < F_HID / 4; ++k4) {
    float4 r = row[k4];
    acc = fmaf(r.x, w2s[(k4 * 4 + 0) * F_OUT + j], acc);
    acc = fmaf(r.y, w2s[(k4 * 4 + 1) * F_OUT + j], acc);
    acc = fmaf(r.z, w2s[(k4 * 4 + 2) * F_OUT + j], acc);
    acc = fmaf(r.w, w2s[(k4 * 4 + 3) * F_OUT + j], acc);
  }
  out[t] = acc;
}

// pull-aggregate layer 2 (16 cols, 16 lanes/node) + self-loop + bias +
// log_softmax over the 16-lane group.
__global__ __launch_bounds__(256) void k_pull16_out(const int* __restrict__ rowptr,
                                                    const int* __restrict__ es,
                                                    const float* __restrict__ en,
                                                    const float* __restrict__ h2,
                                                    const float* __restrict__ dinv,
                                                    const float* __restrict__ b2,
                                                    float* __restrict__ out, int n) {
  int node = blockIdx.x * 16 + (threadIdx.x >> 4);
  if (node >= n) return;
  int lane = threadIdx.x & 15;
  int beg = rowptr[node], end = rowptr[node + 1];
  float acc = 0.f;
  int j = beg;
  for (; j + 1 < end; j += 2) {
    float v0 = h2[(size_t)es[j] * F_OUT + lane];
    float v1 = h2[(size_t)es[j + 1] * F_OUT + lane];
    acc = fmaf(v0, en[j], acc);
    acc = fmaf(v1, en[j + 1], acc);
  }
  if (j < end) acc = fmaf(h2[(size_t)es[j] * F_OUT + lane], en[j], acc);
  float di = dinv[node];
  float v = fmaf(h2[(size_t)node * F_OUT + lane], di * di, acc) + b2[lane];
  float m = v;
#pragma unroll
  for (int off = 8; off; off >>= 1) m = fmaxf(m, __shfl_xor(m, off, 16));
  float ex = expf(v - m);
  float s = ex;
#pragma unroll
  for (int off = 8; off; off >>= 1) s += __shfl_xor(s, off, 16);
  out[(size_t)node * F_OUT + lane] = v - m - logf(s);
}

extern "C" void kernel_launch(void* const* d_in, const int* in_sizes, int n_in,
                              void* d_out, int out_size, void* d_ws, size_t ws_size,
                              hipStream_t stream) {
  const float* x  = (const float*)d_in[0];
  const int*   ei = (const int*)d_in[1];
  const float* ew = (const float*)d_in[2];
  const float* W1 = (const float*)d_in[3];
  const float* b1 = (const float*)d_in[4];
  const float* W2 = (const float*)d_in[5];
  const float* b2 = (const float*)d_in[6];
  float* out = (float*)d_out;

  const int fhid = in_sizes[4];         // 128
  const int fin  = in_sizes[3] / fhid;  // 512
  const int n = in_sizes[0] / fin;      // 100000
  const int E = in_sizes[2];            // 1600000
  const int* src = ei;
  const int* dst = ei + E;

  // workspace (4B units):
  // dinv | h1 | agg1 | h2 | cnt/cursor | rowptr | bsum | es | en | W1T(bf16)
  const size_t nr = (size_t)((n + 255) & ~255);
  float* ws     = (float*)d_ws;
  float* dinv   = ws;                       // [nr] (degw then dinv, in place)
  float* h1     = dinv + nr;                // [n*128]
  float* agg1   = h1 + (size_t)n * F_HID;   // [n*128]
  float* h2     = agg1 + (size_t)n * F_HID; // [n*16]
  int*   cnt    = (int*)(h2 + (size_t)n * F_OUT);  // [nr] counts -> cursor
  int*   rowptr = cnt + nr;                 // [n+1]
  int*   bsum   = rowptr + nr;              // [512]
  int*   es     = bsum + 512;               // [E]
  float* en     = (float*)(es + E);         // [E]
  unsigned short* W1T = (unsigned short*)(en + E);  // [128*512] bf16

  hipMemsetAsync(dinv, 0, nr * 4, stream);
  hipMemsetAsync(cnt, 0, nr * 4, stream);

  const int gE = (E + 255) / 256;
  const int gN = (n + 255) / 256;  // 391 blocks
  k_w1t<<<(F_IN * F_HID) / 256, 256, 0, stream>>>(W1, W1T);
  k_cnt_deg<<<gE, 256, 0, stream>>>(dst, ew, cnt, dinv, E);
  k_dinv<<<gN, 256, 0, stream>>>(dinv, n);
  k_scan1<<<gN, 256, 0, stream>>>(cnt, rowptr, bsum, n);
  k_scan2<<<1, 512, 0, stream>>>(bsum, gN);
  k_scan3<<<gN, 256, 0, stream>>>(rowptr, bsum, cnt, n, E);
  k_scatter<<<gE, 256, 0, stream>>>(src, dst, ew, dinv, cnt, es, en, E);
  k_gemm1m<<<(n + 127) / 128, 256, 0, stream>>>(x, W1T, h1, n);
  k_pull128<<<(n + 3) / 4, 256, 0, stream>>>(rowptr, es, en, h1, dinv, b1, agg1, n);
  k_gemm2<<<(n * F_OUT + 255) / 256, 256, 0, stream>>>(agg1, W2, h2, n);
  k_pull16_out<<<(n + 15) / 16, 256, 0, stream>>>(rowptr, es, en, h2, dinv, b2, out, n);
}